// Round 7
// baseline (429.924 us; speedup 1.0000x reference)
//
#include <hip/hip_runtime.h>
#include <hip/hip_bf16.h>
#include <cstdint>

#define B_   2
#define N_   1024
#define DN_  128
#define DE_  16
#define DG_  128
#define MID_ 64
#define OUT_ 128
#define TI_  4
#define PR_ROWS 4

typedef short bf16x8 __attribute__((ext_vector_type(8)));
typedef float f32x4  __attribute__((ext_vector_type(4)));

__device__ inline short f2bf(float f) {
    union { float f; unsigned u; } v; v.f = f;
    unsigned r = v.u + 0x7FFFu + ((v.u >> 16) & 1u);   // RTNE
    return (short)(unsigned short)(r >> 16);
}

__device__ inline unsigned pk2(float lo, float hi) {
    union { __hip_bfloat162 h; unsigned u; } p;
    p.h = __float22bfloat162_rn(make_float2(lo, hi));  // v_cvt_pk_bf16_f32
    return p.u;
}

// ---------------------------------------------------------------------------
// Fused prep kernel (unchanged — not the bottleneck).
// ---------------------------------------------------------------------------
__global__ void __launch_bounds__(384) prep_all(
    const float* __restrict__ features, const float* __restrict__ g_features,
    const float* __restrict__ Wm, const float* __restrict__ bm,
    const float* __restrict__ Wskip, const float* __restrict__ bskip,
    const float* __restrict__ W1, const float* __restrict__ b1,
    const float* __restrict__ W2, const float* __restrict__ b2,
    const float* __restrict__ We, const float* __restrict__ be,
    const float* __restrict__ Wg, const float* __restrict__ bg,
    float* __restrict__ values, float* __restrict__ skipo,
    float* __restrict__ P1x, float* __restrict__ p2,
    float* __restrict__ pg, short* __restrict__ We_frag)
{
    const int t   = threadIdx.x;
    const int blk = blockIdx.x;

    if (blk == 512) {                       // --- We fragment prep ---
        for (int e = t; e < 4 * 64 * 8; e += 384) {
            const int c    = e >> 9;
            const int lane = (e >> 3) & 63;
            const int j    = e & 7;
            const int quad = lane >> 4, s = lane & 15;
            short v = 0;
            if (quad < 2) v = f2bf(We[(quad * 8 + j) * MID_ + c * 16 + s]);
            We_frag[e] = v;
        }
        return;
    }
    if (blk == 513) {                       // --- pg ---
        if (t < MID_) {
            float a0 = bg[t], a1 = bg[t];
            for (int k = 0; k < DG_; ++k) {
                const float w = Wg[k * MID_ + t];
                a0 += g_features[k] * w;
                a1 += g_features[DG_ + k] * w;
            }
            pg[t] = a0; pg[MID_ + t] = a1;
        }
        return;
    }

    // --- per-node projections ---
    const int r0 = blk * PR_ROWS;
    __shared__ float feat[PR_ROWS][DN_];
    for (int idx = t; idx < PR_ROWS * DN_; idx += 384)
        feat[idx >> 7][idx & 127] = features[(size_t)r0 * DN_ + idx];
    __syncthreads();

    const float* W; int c, stride; float base; float* outp; int ostride;
    if (t < 128) {
        W = Wm;    c = t;       stride = OUT_; base = bm[c];
        outp = values + (size_t)r0 * OUT_ + c; ostride = OUT_;
    } else if (t < 256) {
        W = Wskip; c = t - 128; stride = OUT_; base = bskip[c];
        outp = skipo + (size_t)r0 * OUT_ + c;  ostride = OUT_;
    } else if (t < 320) {
        W = W1;    c = t - 256; stride = MID_; base = b1[c] + be[c];
        outp = P1x + (size_t)r0 * MID_ + c;    ostride = MID_;
    } else {
        W = W2;    c = t - 320; stride = MID_; base = b2[c];
        outp = p2 + (size_t)r0 * MID_ + c;     ostride = MID_;
    }

    float acc[PR_ROWS] = {};
    for (int k = 0; k < DN_; ++k) {
        const float w = W[k * stride + c];
        #pragma unroll
        for (int q = 0; q < PR_ROWS; ++q) acc[q] += feat[q][k] * w;
    }
    #pragma unroll
    for (int q = 0; q < PR_ROWS; ++q) outp[q * ostride] = acc[q] + base;
}

// ---------------------------------------------------------------------------
// Main fused kernel: 512 blocks x 512 threads (8 waves), TI=4 i-rows/block.
// Same reuse + pipeline as the 95us R5 kernel, but 2x waves per block:
// 16 waves/CU demand (4 waves/SIMD via launch_bounds) vs R5's 8.
// ---------------------------------------------------------------------------
__global__ void __launch_bounds__(512, 4) gat_main(
    const float* __restrict__ e_features, const float* __restrict__ adj,
    const short* __restrict__ We_frag, const float* __restrict__ Wa,
    const float* __restrict__ values, const float* __restrict__ skipo,
    const float* __restrict__ P1x, const float* __restrict__ p2,
    const float* __restrict__ pg, float* __restrict__ out)
{
    const int t    = threadIdx.x;
    const int wv   = t >> 6;                          // 0..7
    const int l    = t & 63;
    const int quad = l >> 4;
    const int s    = l & 15;
    const int r    = blockIdx.x;
    const int b    = (r >> 2) & 1;                    // XCD -> one batch
    const int i0   = (((r >> 3) << 2) | (r & 3)) * TI_;

    __shared__ float lgP[TI_][N_];                    // 16 KB
    __shared__ float redv[8][16][36];                 // 18 KB (rows 144B, 16B-aligned)
    __shared__ float smax[8], ssum[8];

    // ---- block constants ----
    bf16x8 bfr[4];
    float  wa_r[4], p2i[TI_][4];
    #pragma unroll
    for (int c = 0; c < 4; ++c) {
        bfr[c]  = *(const bf16x8*)&We_frag[(c * 64 + l) * 8];
        wa_r[c] = Wa[c * 16 + s];
        const float pgc = pg[b * MID_ + c * 16 + s];
        #pragma unroll
        for (int ii = 0; ii < TI_; ++ii)
            p2i[ii][c] = p2[((size_t)(b * N_ + i0 + ii)) * MID_ + c * 16 + s] + pgc;
    }
    const size_t erow0 = (size_t)(b * N_ + i0) * N_;

    // ---- Pass A: software-pipelined MFMA logits (8 tiles per wave) ----
    float4 eA[TI_][2];
    if (quad < 2) {
        #pragma unroll
        for (int ii = 0; ii < TI_; ++ii) {
            const float* ep = &e_features[(erow0 + (size_t)ii * N_ + wv * 16 + s) * DE_ + quad * 8];
            eA[ii][0] = *(const float4*)ep;
            eA[ii][1] = *(const float4*)(ep + 4);
        }
    }
    for (int it = 0; it < 8; ++it) {
        const int tile = wv + it * 8;
        const int j0   = tile * 16;

        // pack current tile
        unsigned af[TI_][4];
        #pragma unroll
        for (int ii = 0; ii < TI_; ++ii) {
            if (quad < 2) {
                af[ii][0] = pk2(eA[ii][0].x, eA[ii][0].y);
                af[ii][1] = pk2(eA[ii][0].z, eA[ii][0].w);
                af[ii][2] = pk2(eA[ii][1].x, eA[ii][1].y);
                af[ii][3] = pk2(eA[ii][1].z, eA[ii][1].w);
            } else {
                af[ii][0] = af[ii][1] = af[ii][2] = af[ii][3] = 0u;
            }
        }
        // prefetch next tile (consumed next iteration)
        if (it < 7) {
            const int jn = (tile + 8) * 16;
            if (quad < 2) {
                #pragma unroll
                for (int ii = 0; ii < TI_; ++ii) {
                    const float* ep = &e_features[(erow0 + (size_t)ii * N_ + jn + s) * DE_ + quad * 8];
                    eA[ii][0] = *(const float4*)ep;
                    eA[ii][1] = *(const float4*)(ep + 4);
                }
            }
        }
        // P1x tile (shared by all 4 i-rows)
        float base[4][4];
        {
            const float* pb = &P1x[((size_t)(b * N_) + j0 + quad * 4) * MID_ + s];
            #pragma unroll
            for (int c = 0; c < 4; ++c)
                #pragma unroll
                for (int rr = 0; rr < 4; ++rr)
                    base[c][rr] = pb[rr * MID_ + c * 16];
        }
        #pragma unroll
        for (int ii = 0; ii < TI_; ++ii) {
            union { unsigned u[4]; bf16x8 v; } a;
            a.u[0] = af[ii][0]; a.u[1] = af[ii][1];
            a.u[2] = af[ii][2]; a.u[3] = af[ii][3];
            f32x4 acc[4];
            #pragma unroll
            for (int c = 0; c < 4; ++c) {
                #pragma unroll
                for (int rr = 0; rr < 4; ++rr)
                    acc[c][rr] = base[c][rr] + p2i[ii][c];
                acc[c] = __builtin_amdgcn_mfma_f32_16x16x32_bf16(a.v, bfr[c], acc[c], 0, 0, 0);
            }
            float tt[4];
            #pragma unroll
            for (int rr = 0; rr < 4; ++rr) {
                float x0 = acc[0][rr]; x0 = fmaxf(x0, 0.01f * x0);
                float x1 = acc[1][rr]; x1 = fmaxf(x1, 0.01f * x1);
                float x2 = acc[2][rr]; x2 = fmaxf(x2, 0.01f * x2);
                float x3 = acc[3][rr]; x3 = fmaxf(x3, 0.01f * x3);
                tt[rr] = x0 * wa_r[0] + x1 * wa_r[1] + x2 * wa_r[2] + x3 * wa_r[3];
            }
            #pragma unroll
            for (int o = 1; o < 16; o <<= 1) {
                tt[0] += __shfl_xor(tt[0], o);
                tt[1] += __shfl_xor(tt[1], o);
                tt[2] += __shfl_xor(tt[2], o);
                tt[3] += __shfl_xor(tt[3], o);
            }
            if (s < 4) lgP[ii][j0 + quad * 4 + s] = tt[s];
        }
    }
    __syncthreads();

    // ---- Pass B: masked softmax — 2 waves per plane (p = wv&3, h = wv>>2) ----
    {
        const int p = wv & 3, h = wv >> 2;
        const int o8 = h * 512 + l * 8;
        const size_t arb = (size_t)(b * N_ + i0 + p) * N_;
        float4 lv0 = *(const float4*)&lgP[p][o8];
        float4 lv1 = *(const float4*)&lgP[p][o8 + 4];
        float4 av0 = *(const float4*)&adj[arb + o8];
        float4 av1 = *(const float4*)&adj[arb + o8 + 4];
        const float NEG = -3.4e38f;
        float m = NEG;
        m = fmaxf(m, av0.x > 0.f ? lv0.x : NEG);
        m = fmaxf(m, av0.y > 0.f ? lv0.y : NEG);
        m = fmaxf(m, av0.z > 0.f ? lv0.z : NEG);
        m = fmaxf(m, av0.w > 0.f ? lv0.w : NEG);
        m = fmaxf(m, av1.x > 0.f ? lv1.x : NEG);
        m = fmaxf(m, av1.y > 0.f ? lv1.y : NEG);
        m = fmaxf(m, av1.z > 0.f ? lv1.z : NEG);
        m = fmaxf(m, av1.w > 0.f ? lv1.w : NEG);
        #pragma unroll
        for (int o = 1; o < 64; o <<= 1) m = fmaxf(m, __shfl_xor(m, o));
        if (l == 0) smax[wv] = m;
        __syncthreads();
        m = fmaxf(smax[p], smax[p + 4]);
        float4 e0, e1;
        e0.x = av0.x > 0.f ? __expf(lv0.x - m) : 0.f;
        e0.y = av0.y > 0.f ? __expf(lv0.y - m) : 0.f;
        e0.z = av0.z > 0.f ? __expf(lv0.z - m) : 0.f;
        e0.w = av0.w > 0.f ? __expf(lv0.w - m) : 0.f;
        e1.x = av1.x > 0.f ? __expf(lv1.x - m) : 0.f;
        e1.y = av1.y > 0.f ? __expf(lv1.y - m) : 0.f;
        e1.z = av1.z > 0.f ? __expf(lv1.z - m) : 0.f;
        e1.w = av1.w > 0.f ? __expf(lv1.w - m) : 0.f;
        *(float4*)&lgP[p][o8]     = e0;
        *(float4*)&lgP[p][o8 + 4] = e1;
        float sum = ((e0.x + e0.y) + (e0.z + e0.w)) + ((e1.x + e1.y) + (e1.z + e1.w));
        #pragma unroll
        for (int o = 1; o < 64; o <<= 1) sum += __shfl_xor(sum, o);
        if (l == 0) ssum[wv] = sum;
        __syncthreads();
    }

    // ---- Pass C: (exp @ values) shared across the 4 i-rows ----
    {
        const int cg  = l & 15;                 // channel group (8 ch)
        const int jp  = (wv << 2) | (l >> 4);   // j partition 0..31
        const int ch0 = cg * 8;
        float acc[TI_][8] = {};
        const float* vb = values + (size_t)b * N_ * OUT_ + ch0;
        for (int k = 0; k < 32; ++k) {
            const int j = jp + k * 32;
            float cw[TI_];
            #pragma unroll
            for (int ii = 0; ii < TI_; ++ii) cw[ii] = lgP[ii][j];
            const float* vp = vb + (size_t)j * OUT_;
            const float4 v0 = *(const float4*)vp;
            const float4 v1 = *(const float4*)(vp + 4);
            const float vv[8] = {v0.x, v0.y, v0.z, v0.w, v1.x, v1.y, v1.z, v1.w};
            #pragma unroll
            for (int ii = 0; ii < TI_; ++ii)
                #pragma unroll
                for (int kk = 0; kk < 8; ++kk)
                    acc[ii][kk] += cw[ii] * vv[kk];
        }
        #pragma unroll
        for (int ii = 0; ii < TI_; ++ii)
            #pragma unroll
            for (int kk = 0; kk < 8; ++kk) {
                acc[ii][kk] += __shfl_xor(acc[ii][kk], 16);
                acc[ii][kk] += __shfl_xor(acc[ii][kk], 32);
            }
        if (l < 16) {
            #pragma unroll
            for (int ii = 0; ii < TI_; ++ii)
                #pragma unroll
                for (int q = 0; q < 2; ++q) {
                    float4 w4 = make_float4(acc[ii][q * 4], acc[ii][q * 4 + 1],
                                            acc[ii][q * 4 + 2], acc[ii][q * 4 + 3]);
                    *(float4*)&redv[wv][l][ii * 8 + q * 4] = w4;
                }
        }
    }
    __syncthreads();
    {
        const int ii = t >> 7;                  // 0..3
        const int ch = t & 127;
        const int g  = ch >> 3, kk = ch & 7;
        float sum = 0.f;
        #pragma unroll
        for (int w = 0; w < 8; ++w) sum += redv[w][g][ii * 8 + kk];
        const float inv = 1.0f / (ssum[ii] + ssum[ii + 4]);
        const size_t ob = ((size_t)(b * N_ + i0 + ii)) * OUT_ + ch;
        out[ob] = fmaxf(sum * inv + skipo[ob], 0.f);
    }
}

extern "C" void kernel_launch(void* const* d_in, const int* in_sizes, int n_in,
                              void* d_out, int out_size, void* d_ws, size_t ws_size,
                              hipStream_t stream) {
    const float* features   = (const float*)d_in[0];
    const float* e_features = (const float*)d_in[1];
    const float* g_features = (const float*)d_in[2];
    const float* adj        = (const float*)d_in[3];
    const float* Wm    = (const float*)d_in[4];
    const float* bm    = (const float*)d_in[5];
    const float* Wskip = (const float*)d_in[6];
    const float* bskip = (const float*)d_in[7];
    const float* W1    = (const float*)d_in[8];
    const float* b1    = (const float*)d_in[9];
    const float* W2    = (const float*)d_in[10];
    const float* b2    = (const float*)d_in[11];
    const float* We    = (const float*)d_in[12];
    const float* be    = (const float*)d_in[13];
    const float* Wg    = (const float*)d_in[14];
    const float* bg    = (const float*)d_in[15];
    const float* Wa    = (const float*)d_in[16];
    float* out = (float*)d_out;

    float* ws      = (float*)d_ws;
    float* values  = ws;                    // 262144
    float* skipo   = ws + 262144;           // 262144
    float* P1x     = ws + 524288;           // 131072
    float* p2      = ws + 655360;           // 131072
    float* pg      = ws + 786432;           // 128
    short* We_frag = (short*)(ws + 786560); // 2048 shorts

    prep_all<<<B_ * N_ / PR_ROWS + 2, 384, 0, stream>>>(
        features, g_features, Wm, bm, Wskip, bskip, W1, b1, W2, b2,
        We, be, Wg, bg, values, skipo, P1x, p2, pg, We_frag);
    gat_main<<<B_ * N_ / TI_, 512, 0, stream>>>(
        e_features, adj, We_frag, Wa, values, skipo, P1x, p2, pg, out);
}

// Round 8
// 306.321 us; speedup vs baseline: 1.4035x; 1.4035x over previous
//
#include <hip/hip_runtime.h>
#include <hip/hip_bf16.h>
#include <cstdint>

#define B_   2
#define N_   1024
#define DN_  128
#define DE_  16
#define DG_  128
#define MID_ 64
#define OUT_ 128
#define TI_  4
#define PR_ROWS 4

typedef short bf16x8 __attribute__((ext_vector_type(8)));
typedef float f32x4  __attribute__((ext_vector_type(4)));

__device__ inline short f2bf(float f) {
    union { float f; unsigned u; } v; v.f = f;
    unsigned r = v.u + 0x7FFFu + ((v.u >> 16) & 1u);   // RTNE
    return (short)(unsigned short)(r >> 16);
}

__device__ inline unsigned pk2(float lo, float hi) {
    union { __hip_bfloat162 h; unsigned u; } p;
    p.h = __float22bfloat162_rn(make_float2(lo, hi));  // v_cvt_pk_bf16_f32
    return p.u;
}

// ---------------------------------------------------------------------------
// Fused prep kernel (unchanged — not the bottleneck).
// ---------------------------------------------------------------------------
__global__ void __launch_bounds__(384) prep_all(
    const float* __restrict__ features, const float* __restrict__ g_features,
    const float* __restrict__ Wm, const float* __restrict__ bm,
    const float* __restrict__ Wskip, const float* __restrict__ bskip,
    const float* __restrict__ W1, const float* __restrict__ b1,
    const float* __restrict__ W2, const float* __restrict__ b2,
    const float* __restrict__ We, const float* __restrict__ be,
    const float* __restrict__ Wg, const float* __restrict__ bg,
    float* __restrict__ values, float* __restrict__ skipo,
    float* __restrict__ P1x, float* __restrict__ p2,
    float* __restrict__ pg, short* __restrict__ We_frag)
{
    const int t   = threadIdx.x;
    const int blk = blockIdx.x;

    if (blk == 512) {                       // --- We fragment prep ---
        for (int e = t; e < 4 * 64 * 8; e += 384) {
            const int c    = e >> 9;
            const int lane = (e >> 3) & 63;
            const int j    = e & 7;
            const int quad = lane >> 4, s = lane & 15;
            short v = 0;
            if (quad < 2) v = f2bf(We[(quad * 8 + j) * MID_ + c * 16 + s]);
            We_frag[e] = v;
        }
        return;
    }
    if (blk == 513) {                       // --- pg ---
        if (t < MID_) {
            float a0 = bg[t], a1 = bg[t];
            for (int k = 0; k < DG_; ++k) {
                const float w = Wg[k * MID_ + t];
                a0 += g_features[k] * w;
                a1 += g_features[DG_ + k] * w;
            }
            pg[t] = a0; pg[MID_ + t] = a1;
        }
        return;
    }

    // --- per-node projections ---
    const int r0 = blk * PR_ROWS;
    __shared__ float feat[PR_ROWS][DN_];
    for (int idx = t; idx < PR_ROWS * DN_; idx += 384)
        feat[idx >> 7][idx & 127] = features[(size_t)r0 * DN_ + idx];
    __syncthreads();

    const float* W; int c, stride; float base; float* outp; int ostride;
    if (t < 128) {
        W = Wm;    c = t;       stride = OUT_; base = bm[c];
        outp = values + (size_t)r0 * OUT_ + c; ostride = OUT_;
    } else if (t < 256) {
        W = Wskip; c = t - 128; stride = OUT_; base = bskip[c];
        outp = skipo + (size_t)r0 * OUT_ + c;  ostride = OUT_;
    } else if (t < 320) {
        W = W1;    c = t - 256; stride = MID_; base = b1[c] + be[c];
        outp = P1x + (size_t)r0 * MID_ + c;    ostride = MID_;
    } else {
        W = W2;    c = t - 320; stride = MID_; base = b2[c];
        outp = p2 + (size_t)r0 * MID_ + c;     ostride = MID_;
    }

    float acc[PR_ROWS] = {};
    for (int k = 0; k < DN_; ++k) {
        const float w = W[k * stride + c];
        #pragma unroll
        for (int q = 0; q < PR_ROWS; ++q) acc[q] += feat[q][k] * w;
    }
    #pragma unroll
    for (int q = 0; q < PR_ROWS; ++q) outp[q * ostride] = acc[q] + base;
}

// ---------------------------------------------------------------------------
// Kernel 1: masked logits for a (4 i-rows x 256 j) tile.  2048 blocks x 256
// threads — 4x the grid of the fused R5 kernel, same verified Pass-A code.
// Stores adj-masked logits (-3.4e38 where no edge) to lgG (8 MB scratch).
// ---------------------------------------------------------------------------
__global__ void __launch_bounds__(256) gat_logits(
    const float* __restrict__ e_features, const float* __restrict__ adj,
    const short* __restrict__ We_frag, const float* __restrict__ Wa,
    const float* __restrict__ P1x, const float* __restrict__ p2,
    const float* __restrict__ pg, float* __restrict__ lgG)
{
    const int t     = threadIdx.x;
    const int wv    = t >> 6;
    const int l     = t & 63;
    const int quad  = l >> 4;
    const int s     = l & 15;
    const int r     = blockIdx.x;
    const int jc    = r & 3;                 // j-chunk
    const int b     = (r >> 2) & 1;          // XCDs 0-3 -> b0, 4-7 -> b1
    const int i0    = (r >> 3) * TI_;
    const int jbase = jc * 256;

    __shared__ float lgL[TI_][256];

    bf16x8 bfr[4];
    float  wa_r[4], p2i[TI_][4];
    #pragma unroll
    for (int c = 0; c < 4; ++c) {
        bfr[c]  = *(const bf16x8*)&We_frag[(c * 64 + l) * 8];
        wa_r[c] = Wa[c * 16 + s];
        const float pgc = pg[b * MID_ + c * 16 + s];
        #pragma unroll
        for (int ii = 0; ii < TI_; ++ii)
            p2i[ii][c] = p2[((size_t)(b * N_ + i0 + ii)) * MID_ + c * 16 + s] + pgc;
    }
    const size_t erow0 = (size_t)(b * N_ + i0) * N_;

    // software-pipelined MFMA logits: 4 tiles per wave within the chunk
    float4 eA[TI_][2];
    if (quad < 2) {
        #pragma unroll
        for (int ii = 0; ii < TI_; ++ii) {
            const float* ep = &e_features[(erow0 + (size_t)ii * N_ + jbase + wv * 16 + s) * DE_ + quad * 8];
            eA[ii][0] = *(const float4*)ep;
            eA[ii][1] = *(const float4*)(ep + 4);
        }
    }
    for (int it = 0; it < 4; ++it) {
        const int j0 = jbase + (wv + it * 4) * 16;

        unsigned af[TI_][4];
        #pragma unroll
        for (int ii = 0; ii < TI_; ++ii) {
            if (quad < 2) {
                af[ii][0] = pk2(eA[ii][0].x, eA[ii][0].y);
                af[ii][1] = pk2(eA[ii][0].z, eA[ii][0].w);
                af[ii][2] = pk2(eA[ii][1].x, eA[ii][1].y);
                af[ii][3] = pk2(eA[ii][1].z, eA[ii][1].w);
            } else {
                af[ii][0] = af[ii][1] = af[ii][2] = af[ii][3] = 0u;
            }
        }
        if (it < 3) {
            const int jn = jbase + (wv + (it + 1) * 4) * 16;
            if (quad < 2) {
                #pragma unroll
                for (int ii = 0; ii < TI_; ++ii) {
                    const float* ep = &e_features[(erow0 + (size_t)ii * N_ + jn + s) * DE_ + quad * 8];
                    eA[ii][0] = *(const float4*)ep;
                    eA[ii][1] = *(const float4*)(ep + 4);
                }
            }
        }
        float base[4][4];
        {
            const float* pb = &P1x[((size_t)(b * N_) + j0 + quad * 4) * MID_ + s];
            #pragma unroll
            for (int c = 0; c < 4; ++c)
                #pragma unroll
                for (int rr = 0; rr < 4; ++rr)
                    base[c][rr] = pb[rr * MID_ + c * 16];
        }
        #pragma unroll
        for (int ii = 0; ii < TI_; ++ii) {
            union { unsigned u[4]; bf16x8 v; } a;
            a.u[0] = af[ii][0]; a.u[1] = af[ii][1];
            a.u[2] = af[ii][2]; a.u[3] = af[ii][3];
            f32x4 acc[4];
            #pragma unroll
            for (int c = 0; c < 4; ++c) {
                #pragma unroll
                for (int rr = 0; rr < 4; ++rr)
                    acc[c][rr] = base[c][rr] + p2i[ii][c];
                acc[c] = __builtin_amdgcn_mfma_f32_16x16x32_bf16(a.v, bfr[c], acc[c], 0, 0, 0);
            }
            float tt[4];
            #pragma unroll
            for (int rr = 0; rr < 4; ++rr) {
                float x0 = acc[0][rr]; x0 = fmaxf(x0, 0.01f * x0);
                float x1 = acc[1][rr]; x1 = fmaxf(x1, 0.01f * x1);
                float x2 = acc[2][rr]; x2 = fmaxf(x2, 0.01f * x2);
                float x3 = acc[3][rr]; x3 = fmaxf(x3, 0.01f * x3);
                tt[rr] = x0 * wa_r[0] + x1 * wa_r[1] + x2 * wa_r[2] + x3 * wa_r[3];
            }
            #pragma unroll
            for (int o = 1; o < 16; o <<= 1) {
                tt[0] += __shfl_xor(tt[0], o);
                tt[1] += __shfl_xor(tt[1], o);
                tt[2] += __shfl_xor(tt[2], o);
                tt[3] += __shfl_xor(tt[3], o);
            }
            if (s < 4) lgL[ii][j0 - jbase + quad * 4 + s] = tt[s];
        }
    }
    __syncthreads();

    // masked coalesced bulk store
    {
        const int   ii  = t >> 6;
        const int   jl  = (t & 63) * 4;
        const size_t row = (size_t)(b * N_ + i0 + ii);
        float4 lg4 = make_float4(lgL[ii][jl], lgL[ii][jl + 1],
                                 lgL[ii][jl + 2], lgL[ii][jl + 3]);
        const float4 a4 = *(const float4*)&adj[row * N_ + jbase + jl];
        const float NEG = -3.4e38f;
        lg4.x = a4.x > 0.f ? lg4.x : NEG;
        lg4.y = a4.y > 0.f ? lg4.y : NEG;
        lg4.z = a4.z > 0.f ? lg4.z : NEG;
        lg4.w = a4.w > 0.f ? lg4.w : NEG;
        *(float4*)&lgG[row * N_ + jbase + jl] = lg4;
    }
}

// ---------------------------------------------------------------------------
// Kernel 2: softmax over j + coefs@values + skip + relu.  512 blocks x 256
// threads, TI=4 i-rows per block (values rows shared across the 4 i's).
// Masked logits arrive pre-masked; exp(NEG - m) underflows to exactly 0.
// ---------------------------------------------------------------------------
__global__ void __launch_bounds__(256) gat_out(
    const float* __restrict__ lgG, const float* __restrict__ values,
    const float* __restrict__ skipo, float* __restrict__ out)
{
    const int t  = threadIdx.x;
    const int wv = t >> 6;
    const int l  = t & 63;
    const int r  = blockIdx.x;
    const int b  = (r >> 2) & 1;
    const int i0 = (((r >> 3) << 2) | (r & 3)) * TI_;

    __shared__ float lgP[TI_][N_];          // 16 KB
    __shared__ float redv[4][16][36];       // 9 KB
    __shared__ float sinv[TI_];

    #pragma unroll
    for (int ii = 0; ii < TI_; ++ii)
        *(float4*)&lgP[ii][t * 4] =
            *(const float4*)&lgG[(size_t)(b * N_ + i0 + ii) * N_ + t * 4];
    __syncthreads();

    // softmax: wave wv owns plane wv; lane handles j = l + 64q (conflict-free)
    {
        float v[16];
        float m = -3.4e38f;
        #pragma unroll
        for (int q = 0; q < 16; ++q) {
            v[q] = lgP[wv][l + 64 * q];
            m = fmaxf(m, v[q]);
        }
        #pragma unroll
        for (int o = 1; o < 64; o <<= 1) m = fmaxf(m, __shfl_xor(m, o));
        float sum = 0.f;
        #pragma unroll
        for (int q = 0; q < 16; ++q) {
            const float e = __expf(v[q] - m);
            lgP[wv][l + 64 * q] = e;
            sum += e;
        }
        #pragma unroll
        for (int o = 1; o < 64; o <<= 1) sum += __shfl_xor(sum, o);
        if (l == 0) sinv[wv] = 1.0f / sum;
    }
    __syncthreads();

    // Pass C: (exp @ values) shared across the 4 i-rows
    {
        const int cg  = l & 15;                 // channel group (8 ch)
        const int jp  = (wv << 2) | (l >> 4);   // j partition 0..15
        const int ch0 = cg * 8;
        float acc[TI_][8] = {};
        const float* vb = values + (size_t)b * N_ * OUT_ + ch0;
        #pragma unroll 2
        for (int k = 0; k < 64; ++k) {
            const int j = jp + k * 16;
            float cw[TI_];
            #pragma unroll
            for (int ii = 0; ii < TI_; ++ii) cw[ii] = lgP[ii][j];
            const float* vp = vb + (size_t)j * OUT_;
            const float4 v0 = *(const float4*)vp;
            const float4 v1 = *(const float4*)(vp + 4);
            const float vv[8] = {v0.x, v0.y, v0.z, v0.w, v1.x, v1.y, v1.z, v1.w};
            #pragma unroll
            for (int ii = 0; ii < TI_; ++ii)
                #pragma unroll
                for (int kk = 0; kk < 8; ++kk)
                    acc[ii][kk] += cw[ii] * vv[kk];
        }
        #pragma unroll
        for (int ii = 0; ii < TI_; ++ii)
            #pragma unroll
            for (int kk = 0; kk < 8; ++kk) {
                acc[ii][kk] += __shfl_xor(acc[ii][kk], 16);
                acc[ii][kk] += __shfl_xor(acc[ii][kk], 32);
            }
        if (l < 16) {
            #pragma unroll
            for (int ii = 0; ii < TI_; ++ii)
                #pragma unroll
                for (int q = 0; q < 2; ++q) {
                    float4 w4 = make_float4(acc[ii][q * 4], acc[ii][q * 4 + 1],
                                            acc[ii][q * 4 + 2], acc[ii][q * 4 + 3]);
                    *(float4*)&redv[wv][l][ii * 8 + q * 4] = w4;
                }
        }
    }
    __syncthreads();
    {
        const int ch = t & 127, g = ch >> 3, kk = ch & 7;
        #pragma unroll
        for (int p = 0; p < 2; ++p) {
            const int ii = (t >> 7) + 2 * p;
            const float sum = redv[0][g][ii * 8 + kk] + redv[1][g][ii * 8 + kk]
                            + redv[2][g][ii * 8 + kk] + redv[3][g][ii * 8 + kk];
            const size_t ob = ((size_t)(b * N_ + i0 + ii)) * OUT_ + ch;
            out[ob] = fmaxf(sum * sinv[ii] + skipo[ob], 0.f);
        }
    }
}

// ---------------------------------------------------------------------------
// Fallback fused kernel (R5 structure, 95us) — used only if ws is too small
// for the 8 MB logits buffer.  512 blocks x 256 threads, full j per block.
// ---------------------------------------------------------------------------
__global__ void __launch_bounds__(256) gat_fused(
    const float* __restrict__ e_features, const float* __restrict__ adj,
    const short* __restrict__ We_frag, const float* __restrict__ Wa,
    const float* __restrict__ values, const float* __restrict__ skipo,
    const float* __restrict__ P1x, const float* __restrict__ p2,
    const float* __restrict__ pg, float* __restrict__ out)
{
    const int t    = threadIdx.x;
    const int wv   = t >> 6;
    const int l    = t & 63;
    const int quad = l >> 4;
    const int s    = l & 15;
    const int r    = blockIdx.x;
    const int b    = (r >> 2) & 1;
    const int i0   = (((r >> 3) << 2) | (r & 3)) * TI_;

    __shared__ float lgP[TI_][N_];
    __shared__ float redv[4][16][36];
    __shared__ float sinv[TI_];

    bf16x8 bfr[4];
    float  wa_r[4], p2i[TI_][4];
    #pragma unroll
    for (int c = 0; c < 4; ++c) {
        bfr[c]  = *(const bf16x8*)&We_frag[(c * 64 + l) * 8];
        wa_r[c] = Wa[c * 16 + s];
        const float pgc = pg[b * MID_ + c * 16 + s];
        #pragma unroll
        for (int ii = 0; ii < TI_; ++ii)
            p2i[ii][c] = p2[((size_t)(b * N_ + i0 + ii)) * MID_ + c * 16 + s] + pgc;
    }
    const size_t erow0 = (size_t)(b * N_ + i0) * N_;

    float4 eA[TI_][2];
    if (quad < 2) {
        #pragma unroll
        for (int ii = 0; ii < TI_; ++ii) {
            const float* ep = &e_features[(erow0 + (size_t)ii * N_ + wv * 16 + s) * DE_ + quad * 8];
            eA[ii][0] = *(const float4*)ep;
            eA[ii][1] = *(const float4*)(ep + 4);
        }
    }
    for (int it = 0; it < 16; ++it) {
        const int j0 = (wv + it * 4) * 16;
        unsigned af[TI_][4];
        #pragma unroll
        for (int ii = 0; ii < TI_; ++ii) {
            if (quad < 2) {
                af[ii][0] = pk2(eA[ii][0].x, eA[ii][0].y);
                af[ii][1] = pk2(eA[ii][0].z, eA[ii][0].w);
                af[ii][2] = pk2(eA[ii][1].x, eA[ii][1].y);
                af[ii][3] = pk2(eA[ii][1].z, eA[ii][1].w);
            } else {
                af[ii][0] = af[ii][1] = af[ii][2] = af[ii][3] = 0u;
            }
        }
        if (it < 15) {
            const int jn = (wv + (it + 1) * 4) * 16;
            if (quad < 2) {
                #pragma unroll
                for (int ii = 0; ii < TI_; ++ii) {
                    const float* ep = &e_features[(erow0 + (size_t)ii * N_ + jn + s) * DE_ + quad * 8];
                    eA[ii][0] = *(const float4*)ep;
                    eA[ii][1] = *(const float4*)(ep + 4);
                }
            }
        }
        float base[4][4];
        {
            const float* pb = &P1x[((size_t)(b * N_) + j0 + quad * 4) * MID_ + s];
            #pragma unroll
            for (int c = 0; c < 4; ++c)
                #pragma unroll
                for (int rr = 0; rr < 4; ++rr)
                    base[c][rr] = pb[rr * MID_ + c * 16];
        }
        #pragma unroll
        for (int ii = 0; ii < TI_; ++ii) {
            union { unsigned u[4]; bf16x8 v; } a;
            a.u[0] = af[ii][0]; a.u[1] = af[ii][1];
            a.u[2] = af[ii][2]; a.u[3] = af[ii][3];
            f32x4 acc[4];
            #pragma unroll
            for (int c = 0; c < 4; ++c) {
                #pragma unroll
                for (int rr = 0; rr < 4; ++rr)
                    acc[c][rr] = base[c][rr] + p2i[ii][c];
                acc[c] = __builtin_amdgcn_mfma_f32_16x16x32_bf16(a.v, bfr[c], acc[c], 0, 0, 0);
            }
            float tt[4];
            #pragma unroll
            for (int rr = 0; rr < 4; ++rr) {
                float x0 = acc[0][rr]; x0 = fmaxf(x0, 0.01f * x0);
                float x1 = acc[1][rr]; x1 = fmaxf(x1, 0.01f * x1);
                float x2 = acc[2][rr]; x2 = fmaxf(x2, 0.01f * x2);
                float x3 = acc[3][rr]; x3 = fmaxf(x3, 0.01f * x3);
                tt[rr] = x0 * wa_r[0] + x1 * wa_r[1] + x2 * wa_r[2] + x3 * wa_r[3];
            }
            #pragma unroll
            for (int o = 1; o < 16; o <<= 1) {
                tt[0] += __shfl_xor(tt[0], o);
                tt[1] += __shfl_xor(tt[1], o);
                tt[2] += __shfl_xor(tt[2], o);
                tt[3] += __shfl_xor(tt[3], o);
            }
            if (s < 4) lgP[ii][j0 + quad * 4 + s] = tt[s];
        }
    }
    __syncthreads();

    // masked softmax, wave wv owns plane wv
    {
        const size_t arb = (size_t)(b * N_ + i0 + wv) * N_;
        float v[16];
        float m = -3.4e38f;
        #pragma unroll
        for (int q = 0; q < 16; ++q) {
            const float av = adj[arb + l + 64 * q];
            const float lv = lgP[wv][l + 64 * q];
            v[q] = av > 0.f ? lv : -3.4e38f;
            m = fmaxf(m, v[q]);
        }
        #pragma unroll
        for (int o = 1; o < 64; o <<= 1) m = fmaxf(m, __shfl_xor(m, o));
        float sum = 0.f;
        #pragma unroll
        for (int q = 0; q < 16; ++q) {
            const float e = __expf(v[q] - m);
            lgP[wv][l + 64 * q] = e;
            sum += e;
        }
        #pragma unroll
        for (int o = 1; o < 64; o <<= 1) sum += __shfl_xor(sum, o);
        if (l == 0) sinv[wv] = 1.0f / sum;
    }
    __syncthreads();

    // Pass C (same as gat_out)
    {
        const int cg  = l & 15;
        const int jp  = (wv << 2) | (l >> 4);
        const int ch0 = cg * 8;
        float acc[TI_][8] = {};
        const float* vb = values + (size_t)b * N_ * OUT_ + ch0;
        #pragma unroll 2
        for (int k = 0; k < 64; ++k) {
            const int j = jp + k * 16;
            float cw[TI_];
            #pragma unroll
            for (int ii = 0; ii < TI_; ++ii) cw[ii] = lgP[ii][j];
            const float* vp = vb + (size_t)j * OUT_;
            const float4 v0 = *(const float4*)vp;
            const float4 v1 = *(const float4*)(vp + 4);
            const float vv[8] = {v0.x, v0.y, v0.z, v0.w, v1.x, v1.y, v1.z, v1.w};
            #pragma unroll
            for (int ii = 0; ii < TI_; ++ii)
                #pragma unroll
                for (int kk = 0; kk < 8; ++kk)
                    acc[ii][kk] += cw[ii] * vv[kk];
        }
        #pragma unroll
        for (int ii = 0; ii < TI_; ++ii)
            #pragma unroll
            for (int kk = 0; kk < 8; ++kk) {
                acc[ii][kk] += __shfl_xor(acc[ii][kk], 16);
                acc[ii][kk] += __shfl_xor(acc[ii][kk], 32);
            }
        if (l < 16) {
            #pragma unroll
            for (int ii = 0; ii < TI_; ++ii)
                #pragma unroll
                for (int q = 0; q < 2; ++q) {
                    float4 w4 = make_float4(acc[ii][q * 4], acc[ii][q * 4 + 1],
                                            acc[ii][q * 4 + 2], acc[ii][q * 4 + 3]);
                    *(float4*)&redv[wv][l][ii * 8 + q * 4] = w4;
                }
        }
    }
    __syncthreads();
    {
        const int ch = t & 127, g = ch >> 3, kk = ch & 7;
        #pragma unroll
        for (int p = 0; p < 2; ++p) {
            const int ii = (t >> 7) + 2 * p;
            const float sum = redv[0][g][ii * 8 + kk] + redv[1][g][ii * 8 + kk]
                            + redv[2][g][ii * 8 + kk] + redv[3][g][ii * 8 + kk];
            const size_t ob = ((size_t)(b * N_ + i0 + ii)) * OUT_ + ch;
            out[ob] = fmaxf(sum * sinv[ii] + skipo[ob], 0.f);
        }
    }
}

extern "C" void kernel_launch(void* const* d_in, const int* in_sizes, int n_in,
                              void* d_out, int out_size, void* d_ws, size_t ws_size,
                              hipStream_t stream) {
    const float* features   = (const float*)d_in[0];
    const float* e_features = (const float*)d_in[1];
    const float* g_features = (const float*)d_in[2];
    const float* adj        = (const float*)d_in[3];
    const float* Wm    = (const float*)d_in[4];
    const float* bm    = (const float*)d_in[5];
    const float* Wskip = (const float*)d_in[6];
    const float* bskip = (const float*)d_in[7];
    const float* W1    = (const float*)d_in[8];
    const float* b1    = (const float*)d_in[9];
    const float* W2    = (const float*)d_in[10];
    const float* b2    = (const float*)d_in[11];
    const float* We    = (const float*)d_in[12];
    const float* be    = (const float*)d_in[13];
    const float* Wg    = (const float*)d_in[14];
    const float* bg    = (const float*)d_in[15];
    const float* Wa    = (const float*)d_in[16];
    float* out = (float*)d_out;

    float* ws      = (float*)d_ws;
    float* values  = ws;                    // 262144
    float* skipo   = ws + 262144;           // 262144
    float* P1x     = ws + 524288;           // 131072
    float* p2      = ws + 655360;           // 131072
    float* pg      = ws + 786432;           // 128
    short* We_frag = (short*)(ws + 786560); // 2048 shorts = 1024 floats
    float* lgG     = ws + 787584;           // 2*1024*1024 floats (8 MB)

    prep_all<<<B_ * N_ / PR_ROWS + 2, 384, 0, stream>>>(
        features, g_features, Wm, bm, Wskip, bskip, W1, b1, W2, b2,
        We, be, Wg, bg, values, skipo, P1x, p2, pg, We_frag);

    const size_t need = (size_t)(787584 + B_ * N_ * N_) * sizeof(float);
    if (ws_size >= need) {
        gat_logits<<<B_ * N_ / TI_ * 4, 256, 0, stream>>>(
            e_features, adj, We_frag, Wa, P1x, p2, pg, lgG);
        gat_out<<<B_ * N_ / TI_, 256, 0, stream>>>(lgG, values, skipo, out);
    } else {
        gat_fused<<<B_ * N_ / TI_, 256, 0, stream>>>(
            e_features, adj, We_frag, Wa, values, skipo, P1x, p2, pg, out);
    }
}